// Round 12
// baseline (22403.572 us; speedup 1.0000x reference)
//
#include <hip/hip_runtime.h>
#include <hip/hip_bf16.h>

// ---------------------------------------------------------------------------
// LSTMCell scan, T=4096, HID=2048, input=2048 (src||dst), fp32 in/out.
//   K1 init_tags : reset tagged h-broadcast buffers
//   K2 xg_gemm   : xg = x @ W_ih^T + (b_ih+b_hh), fp16 MFMA -> ws,
//                  layout [t][wg][gate][m] (64B per WG per step)
//   K3 lstm_scan : persistent 256 WG x 256 thr (4 waves). R2 skeleton
//                  EXACTLY (best measured: 2.13us/step): W_hh fp16 pinned in
//                  128 VGPRs; per step: single-batch sleep-throttled poll of
//                  own 4 tagged entries -> dots from poll regs -> swizzled
//                  LDS partials -> ONE barrier -> reduce -> gates -> publish.
//                  Plus the two proven-safe additions: 64B xg layout and
//                  one-step-ahead xg register prefetch (hidden under reduce).
// ---------------------------------------------------------------------------

#define T_STEPS 4096
#define FOURH   8192

typedef _Float16 f16;
typedef _Float16 f16x2 __attribute__((ext_vector_type(2)));
typedef _Float16 f16x8 __attribute__((ext_vector_type(8)));
typedef float    f32x4 __attribute__((ext_vector_type(4)));

#if __has_builtin(__builtin_amdgcn_fdot2)
#define FDOT2(a, b, c) __builtin_amdgcn_fdot2((a), (b), (c), false)
#else
#define FDOT2(a, b, c) ((c) + (float)(a)[0] * (float)(b)[0] + (float)(a)[1] * (float)(b)[1])
#endif

// ---------------------------------------------------------------------------
// K1: buffer0 holds h_0 = 0 with tag 1; buffer1 tag 0.
__global__ void init_tags(unsigned long long* __restrict__ hbuf) {
    int i = blockIdx.x * 256 + threadIdx.x;
    if (i < 2048) hbuf[i] = (i < 1024) ? (1ULL << 32) : 0ULL;
}

// ---------------------------------------------------------------------------
// K2: xg = concat(src,dst) @ W_ih^T + (b_ih + b_hh), fp16 output.
// Output layout: xg[t*8192 + wg*32 + gate*8 + m]
#define GBM 128
#define GBN 128
#define GBK 32
#define LDT 40

__global__ __launch_bounds__(256) void xg_gemm(
    const float* __restrict__ src, const float* __restrict__ dst,
    const float* __restrict__ Wih, const float* __restrict__ bi,
    const float* __restrict__ bh, f16* __restrict__ xg) {
    __shared__ __align__(16) f16 As[GBM * LDT];
    __shared__ __align__(16) f16 Bs[GBN * LDT];

    const int tid = threadIdx.x;
    const int bx  = blockIdx.x;
    const int tm  = bx >> 6, tn = bx & 63;
    const int m0  = tm * GBM, n0 = tn * GBN;
    const int lane = tid & 63, wv = tid >> 6;
    const int wm = (wv >> 1) * 64, wn = (wv & 1) * 64;
    const int fr = lane & 15, kg = lane >> 4;

    const int srow = tid >> 1;
    const int sk   = (tid & 1) * 16;

    f32x4 acc[4][4];
#pragma unroll
    for (int i = 0; i < 4; ++i)
#pragma unroll
        for (int j = 0; j < 4; ++j) acc[i][j] = (f32x4){0.f, 0.f, 0.f, 0.f};

    for (int kt = 0; kt < 2048 / GBK; ++kt) {
        const int gk = kt * GBK + sk;
        {
            const float* ap = (gk < 1024) ? (src + (size_t)(m0 + srow) * 1024 + gk)
                                          : (dst + (size_t)(m0 + srow) * 1024 + (gk - 1024));
            float4 fa = *(const float4*)(ap + 0);
            float4 fb = *(const float4*)(ap + 4);
            float4 fc = *(const float4*)(ap + 8);
            float4 fd = *(const float4*)(ap + 12);
            f16x8 lo, hi;
            lo[0] = (f16)fa.x; lo[1] = (f16)fa.y; lo[2] = (f16)fa.z; lo[3] = (f16)fa.w;
            lo[4] = (f16)fb.x; lo[5] = (f16)fb.y; lo[6] = (f16)fb.z; lo[7] = (f16)fb.w;
            hi[0] = (f16)fc.x; hi[1] = (f16)fc.y; hi[2] = (f16)fc.z; hi[3] = (f16)fc.w;
            hi[4] = (f16)fd.x; hi[5] = (f16)fd.y; hi[6] = (f16)fd.z; hi[7] = (f16)fd.w;
            *(f16x8*)&As[srow * LDT + sk]     = lo;
            *(f16x8*)&As[srow * LDT + sk + 8] = hi;
        }
        {
            const float* bp = Wih + (size_t)(n0 + srow) * 2048 + gk;
            float4 fa = *(const float4*)(bp + 0);
            float4 fb = *(const float4*)(bp + 4);
            float4 fc = *(const float4*)(bp + 8);
            float4 fd = *(const float4*)(bp + 12);
            f16x8 lo, hi;
            lo[0] = (f16)fa.x; lo[1] = (f16)fa.y; lo[2] = (f16)fa.z; lo[3] = (f16)fa.w;
            lo[4] = (f16)fb.x; lo[5] = (f16)fb.y; lo[6] = (f16)fb.z; lo[7] = (f16)fb.w;
            hi[0] = (f16)fc.x; hi[1] = (f16)fc.y; hi[2] = (f16)fc.z; hi[3] = (f16)fc.w;
            hi[4] = (f16)fd.x; hi[5] = (f16)fd.y; hi[6] = (f16)fd.z; hi[7] = (f16)fd.w;
            *(f16x8*)&Bs[srow * LDT + sk]     = lo;
            *(f16x8*)&Bs[srow * LDT + sk + 8] = hi;
        }
        __syncthreads();
        f16x8 a[4], b[4];
#pragma unroll
        for (int m = 0; m < 4; ++m) a[m] = *(const f16x8*)&As[(wm + m * 16 + fr) * LDT + kg * 8];
#pragma unroll
        for (int n = 0; n < 4; ++n) b[n] = *(const f16x8*)&Bs[(wn + n * 16 + fr) * LDT + kg * 8];
#pragma unroll
        for (int m = 0; m < 4; ++m)
#pragma unroll
            for (int n = 0; n < 4; ++n)
                acc[m][n] = __builtin_amdgcn_mfma_f32_16x16x32_f16(a[m], b[n], acc[m][n], 0, 0, 0);
        __syncthreads();
    }
#pragma unroll
    for (int n = 0; n < 4; ++n) {
        const int col = n0 + wn + n * 16 + fr;
        const float bias = bi[col] + bh[col];
        const size_t cbase = (size_t)(((col >> 3) & 255) * 32 + (col >> 11) * 8 + (col & 7));
#pragma unroll
        for (int m = 0; m < 4; ++m) {
            const int rb = m0 + wm + m * 16 + kg * 4;   // = timestep t
#pragma unroll
            for (int r = 0; r < 4; ++r)
                xg[(size_t)(rb + r) * FOURH + cbase] = (f16)(acc[m][n][r] + bias);
        }
    }
}

// ---------------------------------------------------------------------------
// K3: persistent scan. 256 WGs x 256 threads (4 waves). R2 skeleton.
// WG w owns m in [8w, 8w+8), rows r in [0,32): m = r>>2, g = r&3.
// Wave v owns k-quarter [512v, 512v+512) == entries [256v, 256v+256).
// Lane l polls entries 256v+4l+{0..3}; weights wreg[32][4] f16x2 pinned.
__global__ __launch_bounds__(256, 1) void lstm_scan(
    const float* __restrict__ Whh, const f16* __restrict__ xg,
    unsigned long long* __restrict__ hbuf, float* __restrict__ out) {
    const int w    = blockIdx.x;
    const int tid  = threadIdx.x;
    const int lane = tid & 63;
    const int wv   = tid >> 6;

    __shared__ float scratch[2][4][32][64];   // [slot][wave][row][lane^swz]

    // ---- load + pin weights: 32 rows x 4 f16x2 = 128 regs ----
    const int k0 = 512 * wv + 8 * lane;
    unsigned wreg[32][4];
#pragma unroll
    for (int r = 0; r < 32; ++r) {
        const size_t row = (size_t)((r & 3) * 2048 + w * 8 + (r >> 2));
        const float4* wp = (const float4*)(Whh + row * 2048 + k0);
        float4 a = wp[0], b = wp[1];
        f16x2 p0; p0[0] = (f16)a.x; p0[1] = (f16)a.y;
        f16x2 p1; p1[0] = (f16)a.z; p1[1] = (f16)a.w;
        f16x2 p2; p2[0] = (f16)b.x; p2[1] = (f16)b.y;
        f16x2 p3; p3[0] = (f16)b.z; p3[1] = (f16)b.w;
        wreg[r][0] = __builtin_bit_cast(unsigned, p0);
        wreg[r][1] = __builtin_bit_cast(unsigned, p1);
        wreg[r][2] = __builtin_bit_cast(unsigned, p2);
        wreg[r][3] = __builtin_bit_cast(unsigned, p3);
    }
#pragma unroll
    for (int r = 0; r < 32; ++r)
#pragma unroll
        for (int i = 0; i < 4; ++i)
            asm volatile("" : "+v"(wreg[r][i]));   // pin: no remat, no resink

    unsigned long long* bb0 = hbuf;
    unsigned long long* bb1 = hbuf + 1024;
    const int e0 = 256 * wv + 4 * lane;

    const int q    = tid & 7;
    const int rR   = tid >> 3;
    const int vR   = q >> 1, halfR = q & 1;
    const int swzR = ((rR & 7) << 2) ^ (vR << 3);
    const int xoff = w * 32 + ((rR & 3) << 3) + (rR >> 2);   // 64B xg layout

    float c_st = 0.f;                      // cell state for m = 2*wv + (lane>=32)
    float xgv_next = (q == 0) ? (float)xg[xoff] : 0.f;   // xg for step 0

    for (int t = 0; t < T_STEPS; ++t) {
        const float xgv = xgv_next;        // this step's xg (q==0 lanes)

        unsigned long long* cur = (t & 1) ? bb1 : bb0;
        const unsigned tagw = (unsigned)(t + 1);

        // ---- R2 poll: single batch in flight, sleep-throttled ----
        unsigned long long p0, p1, p2, p3;
        for (;;) {
            p0 = __hip_atomic_load(cur + e0 + 0, __ATOMIC_RELAXED, __HIP_MEMORY_SCOPE_AGENT);
            p1 = __hip_atomic_load(cur + e0 + 1, __ATOMIC_RELAXED, __HIP_MEMORY_SCOPE_AGENT);
            p2 = __hip_atomic_load(cur + e0 + 2, __ATOMIC_RELAXED, __HIP_MEMORY_SCOPE_AGENT);
            p3 = __hip_atomic_load(cur + e0 + 3, __ATOMIC_RELAXED, __HIP_MEMORY_SCOPE_AGENT);
            if ((unsigned)(p0 >> 32) >= tagw && (unsigned)(p1 >> 32) >= tagw &&
                (unsigned)(p2 >> 32) >= tagw && (unsigned)(p3 >> 32) >= tagw)
                break;
            __builtin_amdgcn_s_sleep(1);
        }
        f16x2 h0 = __builtin_bit_cast(f16x2, (unsigned)p0);
        f16x2 h1 = __builtin_bit_cast(f16x2, (unsigned)p1);
        f16x2 h2 = __builtin_bit_cast(f16x2, (unsigned)p2);
        f16x2 h3 = __builtin_bit_cast(f16x2, (unsigned)p3);

        // ---- 32 row-partials straight from registers -> swizzled LDS ----
        float* sc = &scratch[t & 1][wv][0][0];
#pragma unroll
        for (int r = 0; r < 32; ++r) {
            float a = FDOT2(__builtin_bit_cast(f16x2, wreg[r][0]), h0, 0.f);
            a = FDOT2(__builtin_bit_cast(f16x2, wreg[r][1]), h1, a);
            a = FDOT2(__builtin_bit_cast(f16x2, wreg[r][2]), h2, a);
            a = FDOT2(__builtin_bit_cast(f16x2, wreg[r][3]), h3, a);
            sc[r * 64 + (lane ^ (((r & 7) << 2) ^ (wv << 3)))] = a;
        }
        __syncthreads();   // the ONE barrier per step

        // ---- prefetch next step's xg (consumed next iteration) ----
        if (q == 0 && t + 1 < T_STEPS)
            xgv_next = (float)xg[(size_t)(t + 1) * FOURH + xoff];

        // ---- final reduce: 8 threads per row ----
        const float* sr = &scratch[t & 1][vR][rR][0];
        float s0 = 0.f;
#pragma unroll
        for (int kk = 0; kk < 8; ++kk) {
            const int idx = ((halfR << 5) + (kk << 2)) ^ swzR;
            f32x4 vv = *(const f32x4*)&sr[idx];
            s0 += vv[0] + vv[1] + vv[2] + vv[3];
        }
        s0 += __shfl_xor(s0, 1);
        s0 += __shfl_xor(s0, 2);
        s0 += __shfl_xor(s0, 4);
        s0 += xgv;                         // valid at q==0 lanes (0,8,...,56)

        // ---- gather 4 gates for this lane's m-half; compute c,h ----
        const int base = lane & 32;
        float gi = __shfl(s0, base + 0);
        float gf = __shfl(s0, base + 8);
        float gg = __shfl(s0, base + 16);
        float go = __shfl(s0, base + 24);
        float ig = 1.f / (1.f + __expf(-gi));
        float fg = 1.f / (1.f + __expf(-gf));
        float g  = 1.f - 2.f / (__expf(2.f * gg) + 1.f);
        float og = 1.f / (1.f + __expf(-go));
        float c  = fg * c_st + ig * g;
        c_st = c;
        float h = og * (1.f - 2.f / (__expf(2.f * c) + 1.f));

        if (t == T_STEPS - 1) {
            if ((lane & 31) == 0) out[w * 8 + 2 * wv + (lane >> 5)] = h;
        } else {
            float hh = __shfl(h, 32);      // odd-m h
            if (lane == 0) {
                f16x2 hp; hp[0] = (f16)h; hp[1] = (f16)hh;
                unsigned long long val =
                    ((unsigned long long)(unsigned)(t + 2) << 32) |
                    (unsigned long long)__builtin_bit_cast(unsigned, hp);
                unsigned long long* nxt = (t & 1) ? bb0 : bb1;
                __hip_atomic_store(nxt + (w * 4 + wv), val,
                                   __ATOMIC_RELAXED, __HIP_MEMORY_SCOPE_AGENT);
            }
        }
    }
}

// ---------------------------------------------------------------------------
extern "C" void kernel_launch(void* const* d_in, const int* in_sizes, int n_in,
                              void* d_out, int out_size, void* d_ws, size_t ws_size,
                              hipStream_t stream) {
    const float* src = (const float*)d_in[0];
    const float* dst = (const float*)d_in[1];
    const float* Wih = (const float*)d_in[2];
    const float* Whh = (const float*)d_in[3];
    const float* bi  = (const float*)d_in[4];
    const float* bh  = (const float*)d_in[5];
    float* out = (float*)d_out;

    f16* xg = (f16*)d_ws;
    unsigned long long* hbuf =
        (unsigned long long*)((char*)d_ws + ((size_t)64 << 20));

    hipLaunchKernelGGL(init_tags, dim3(8), dim3(256), 0, stream, hbuf);
    hipLaunchKernelGGL(xg_gemm, dim3((4096 / GBM) * (FOURH / GBN)), dim3(256), 0, stream,
                       src, dst, Wih, bi, bh, xg);
    hipLaunchKernelGGL(lstm_scan, dim3(256), dim3(256), 0, stream, Whh, xg, hbuf, out);
}

// Round 13
// 8927.956 us; speedup vs baseline: 2.5094x; 2.5094x over previous
//
#include <hip/hip_runtime.h>
#include <hip/hip_bf16.h>

// ---------------------------------------------------------------------------
// LSTMCell scan, T=4096, HID=2048, input=2048 (src||dst), fp32 in/out.
// BYTE-FOR-BYTE the round-2 kernel — best measured: 8.73 ms scan, 2.13 us/step.
//   K1 init_tags : reset tagged h-broadcast buffers
//   K2 xg_gemm   : xg = x @ W_ih^T + (b_ih+b_hh), fp16 MFMA -> ws
//   K3 lstm_scan : persistent 256 WG x 256 thr (4 waves). W_hh fp16 PINNED in
//                  128 VGPRs. Per step: single-batch sleep-throttled poll of
//                  own 4 tagged entries -> dots from poll regs -> swizzled
//                  LDS partials -> ONE barrier -> reduce -> gates -> publish.
// ---------------------------------------------------------------------------

#define T_STEPS 4096
#define FOURH   8192

typedef _Float16 f16;
typedef _Float16 f16x2 __attribute__((ext_vector_type(2)));
typedef _Float16 f16x8 __attribute__((ext_vector_type(8)));
typedef float    f32x4 __attribute__((ext_vector_type(4)));

#if __has_builtin(__builtin_amdgcn_fdot2)
#define FDOT2(a, b, c) __builtin_amdgcn_fdot2((a), (b), (c), false)
#else
#define FDOT2(a, b, c) ((c) + (float)(a)[0] * (float)(b)[0] + (float)(a)[1] * (float)(b)[1])
#endif

// ---------------------------------------------------------------------------
// K1: buffer0 holds h_0 = 0 with tag 1; buffer1 tag 0.
__global__ void init_tags(unsigned long long* __restrict__ hbuf) {
    int i = blockIdx.x * 256 + threadIdx.x;
    if (i < 2048) hbuf[i] = (i < 1024) ? (1ULL << 32) : 0ULL;
}

// ---------------------------------------------------------------------------
// K2: xg = concat(src,dst) @ W_ih^T + (b_ih + b_hh), fp16 output.
#define GBM 128
#define GBN 128
#define GBK 32
#define LDT 40

__global__ __launch_bounds__(256) void xg_gemm(
    const float* __restrict__ src, const float* __restrict__ dst,
    const float* __restrict__ Wih, const float* __restrict__ bi,
    const float* __restrict__ bh, f16* __restrict__ xg) {
    __shared__ __align__(16) f16 As[GBM * LDT];
    __shared__ __align__(16) f16 Bs[GBN * LDT];

    const int tid = threadIdx.x;
    const int bx  = blockIdx.x;
    const int tm  = bx >> 6, tn = bx & 63;
    const int m0  = tm * GBM, n0 = tn * GBN;
    const int lane = tid & 63, wv = tid >> 6;
    const int wm = (wv >> 1) * 64, wn = (wv & 1) * 64;
    const int fr = lane & 15, kg = lane >> 4;

    const int srow = tid >> 1;
    const int sk   = (tid & 1) * 16;

    f32x4 acc[4][4];
#pragma unroll
    for (int i = 0; i < 4; ++i)
#pragma unroll
        for (int j = 0; j < 4; ++j) acc[i][j] = (f32x4){0.f, 0.f, 0.f, 0.f};

    for (int kt = 0; kt < 2048 / GBK; ++kt) {
        const int gk = kt * GBK + sk;
        {
            const float* ap = (gk < 1024) ? (src + (size_t)(m0 + srow) * 1024 + gk)
                                          : (dst + (size_t)(m0 + srow) * 1024 + (gk - 1024));
            float4 fa = *(const float4*)(ap + 0);
            float4 fb = *(const float4*)(ap + 4);
            float4 fc = *(const float4*)(ap + 8);
            float4 fd = *(const float4*)(ap + 12);
            f16x8 lo, hi;
            lo[0] = (f16)fa.x; lo[1] = (f16)fa.y; lo[2] = (f16)fa.z; lo[3] = (f16)fa.w;
            lo[4] = (f16)fb.x; lo[5] = (f16)fb.y; lo[6] = (f16)fb.z; lo[7] = (f16)fb.w;
            hi[0] = (f16)fc.x; hi[1] = (f16)fc.y; hi[2] = (f16)fc.z; hi[3] = (f16)fc.w;
            hi[4] = (f16)fd.x; hi[5] = (f16)fd.y; hi[6] = (f16)fd.z; hi[7] = (f16)fd.w;
            *(f16x8*)&As[srow * LDT + sk]     = lo;
            *(f16x8*)&As[srow * LDT + sk + 8] = hi;
        }
        {
            const float* bp = Wih + (size_t)(n0 + srow) * 2048 + gk;
            float4 fa = *(const float4*)(bp + 0);
            float4 fb = *(const float4*)(bp + 4);
            float4 fc = *(const float4*)(bp + 8);
            float4 fd = *(const float4*)(bp + 12);
            f16x8 lo, hi;
            lo[0] = (f16)fa.x; lo[1] = (f16)fa.y; lo[2] = (f16)fa.z; lo[3] = (f16)fa.w;
            lo[4] = (f16)fb.x; lo[5] = (f16)fb.y; lo[6] = (f16)fb.z; lo[7] = (f16)fb.w;
            hi[0] = (f16)fc.x; hi[1] = (f16)fc.y; hi[2] = (f16)fc.z; hi[3] = (f16)fc.w;
            hi[4] = (f16)fd.x; hi[5] = (f16)fd.y; hi[6] = (f16)fd.z; hi[7] = (f16)fd.w;
            *(f16x8*)&Bs[srow * LDT + sk]     = lo;
            *(f16x8*)&Bs[srow * LDT + sk + 8] = hi;
        }
        __syncthreads();
        f16x8 a[4], b[4];
#pragma unroll
        for (int m = 0; m < 4; ++m) a[m] = *(const f16x8*)&As[(wm + m * 16 + fr) * LDT + kg * 8];
#pragma unroll
        for (int n = 0; n < 4; ++n) b[n] = *(const f16x8*)&Bs[(wn + n * 16 + fr) * LDT + kg * 8];
#pragma unroll
        for (int m = 0; m < 4; ++m)
#pragma unroll
            for (int n = 0; n < 4; ++n)
                acc[m][n] = __builtin_amdgcn_mfma_f32_16x16x32_f16(a[m], b[n], acc[m][n], 0, 0, 0);
        __syncthreads();
    }
#pragma unroll
    for (int n = 0; n < 4; ++n) {
        const int col = n0 + wn + n * 16 + fr;
        const float bias = bi[col] + bh[col];
#pragma unroll
        for (int m = 0; m < 4; ++m) {
            const int rb = m0 + wm + m * 16 + kg * 4;
#pragma unroll
            for (int r = 0; r < 4; ++r)
                xg[(size_t)(rb + r) * FOURH + col] = (f16)(acc[m][n][r] + bias);
        }
    }
}

// ---------------------------------------------------------------------------
// K3: persistent scan. 256 WGs x 256 threads (4 waves).
// WG w owns m in [8w, 8w+8), rows r in [0,32): m = r>>2, g = r&3.
// Wave v owns k-quarter [512v, 512v+512) == entries [256v, 256v+256).
// Lane l polls entries 256v+4l+{0..3}; weights wreg[32][4] f16x2 pinned.
__global__ __launch_bounds__(256, 1) void lstm_scan(
    const float* __restrict__ Whh, const f16* __restrict__ xg,
    unsigned long long* __restrict__ hbuf, float* __restrict__ out) {
    const int w    = blockIdx.x;
    const int tid  = threadIdx.x;
    const int lane = tid & 63;
    const int wv   = tid >> 6;

    __shared__ float scratch[2][4][32][64];   // [slot][wave][row][lane^swz]

    // ---- load + pin weights: 32 rows x 4 f16x2 = 128 regs ----
    const int k0 = 512 * wv + 8 * lane;
    unsigned wreg[32][4];
#pragma unroll
    for (int r = 0; r < 32; ++r) {
        const size_t row = (size_t)((r & 3) * 2048 + w * 8 + (r >> 2));
        const float4* wp = (const float4*)(Whh + row * 2048 + k0);
        float4 a = wp[0], b = wp[1];
        f16x2 p0; p0[0] = (f16)a.x; p0[1] = (f16)a.y;
        f16x2 p1; p1[0] = (f16)a.z; p1[1] = (f16)a.w;
        f16x2 p2; p2[0] = (f16)b.x; p2[1] = (f16)b.y;
        f16x2 p3; p3[0] = (f16)b.z; p3[1] = (f16)b.w;
        wreg[r][0] = __builtin_bit_cast(unsigned, p0);
        wreg[r][1] = __builtin_bit_cast(unsigned, p1);
        wreg[r][2] = __builtin_bit_cast(unsigned, p2);
        wreg[r][3] = __builtin_bit_cast(unsigned, p3);
    }
#pragma unroll
    for (int r = 0; r < 32; ++r)
#pragma unroll
        for (int i = 0; i < 4; ++i)
            asm volatile("" : "+v"(wreg[r][i]));   // pin: no remat, no resink

    unsigned long long* bb0 = hbuf;
    unsigned long long* bb1 = hbuf + 1024;
    const int e0 = 256 * wv + 4 * lane;

    const int q    = tid & 7;
    const int rR   = tid >> 3;
    const int vR   = q >> 1, halfR = q & 1;
    const int swzR = ((rR & 7) << 2) ^ (vR << 3);
    const int xcol = (rR & 3) * 2048 + w * 8 + (rR >> 2);

    float c_st = 0.f;                      // cell state for m = 2*wv + (lane>=32)

    for (int t = 0; t < T_STEPS; ++t) {
        // xg for the row this thread reduces (only q==0 uses it)
        float xgv = 0.f;
        if (q == 0) xgv = (float)xg[(size_t)t * FOURH + xcol];

        unsigned long long* cur = (t & 1) ? bb1 : bb0;
        const unsigned tagw = (unsigned)(t + 1);
        unsigned long long p0, p1, p2, p3;
        for (;;) {
            p0 = __hip_atomic_load(cur + e0 + 0, __ATOMIC_RELAXED, __HIP_MEMORY_SCOPE_AGENT);
            p1 = __hip_atomic_load(cur + e0 + 1, __ATOMIC_RELAXED, __HIP_MEMORY_SCOPE_AGENT);
            p2 = __hip_atomic_load(cur + e0 + 2, __ATOMIC_RELAXED, __HIP_MEMORY_SCOPE_AGENT);
            p3 = __hip_atomic_load(cur + e0 + 3, __ATOMIC_RELAXED, __HIP_MEMORY_SCOPE_AGENT);
            if ((unsigned)(p0 >> 32) >= tagw && (unsigned)(p1 >> 32) >= tagw &&
                (unsigned)(p2 >> 32) >= tagw && (unsigned)(p3 >> 32) >= tagw)
                break;
            __builtin_amdgcn_s_sleep(1);
        }
        f16x2 h0 = __builtin_bit_cast(f16x2, (unsigned)p0);
        f16x2 h1 = __builtin_bit_cast(f16x2, (unsigned)p1);
        f16x2 h2 = __builtin_bit_cast(f16x2, (unsigned)p2);
        f16x2 h3 = __builtin_bit_cast(f16x2, (unsigned)p3);

        // ---- 32 row-partials straight from registers -> swizzled LDS ----
        float* sc = &scratch[t & 1][wv][0][0];
#pragma unroll
        for (int r = 0; r < 32; ++r) {
            float a = FDOT2(__builtin_bit_cast(f16x2, wreg[r][0]), h0, 0.f);
            a = FDOT2(__builtin_bit_cast(f16x2, wreg[r][1]), h1, a);
            a = FDOT2(__builtin_bit_cast(f16x2, wreg[r][2]), h2, a);
            a = FDOT2(__builtin_bit_cast(f16x2, wreg[r][3]), h3, a);
            sc[r * 64 + (lane ^ (((r & 7) << 2) ^ (wv << 3)))] = a;
        }
        __syncthreads();   // the ONE barrier per step

        // ---- final reduce: 8 threads per row ----
        const float* sr = &scratch[t & 1][vR][rR][0];
        float s0 = 0.f;
#pragma unroll
        for (int kk = 0; kk < 8; ++kk) {
            const int idx = ((halfR << 5) + (kk << 2)) ^ swzR;
            f32x4 vv = *(const f32x4*)&sr[idx];
            s0 += vv[0] + vv[1] + vv[2] + vv[3];
        }
        s0 += __shfl_xor(s0, 1);
        s0 += __shfl_xor(s0, 2);
        s0 += __shfl_xor(s0, 4);
        s0 += xgv;                         // valid at q==0 lanes (0,8,...,56)

        // ---- gather 4 gates for this lane's m-half; compute c,h ----
        const int base = lane & 32;
        float gi = __shfl(s0, base + 0);
        float gf = __shfl(s0, base + 8);
        float gg = __shfl(s0, base + 16);
        float go = __shfl(s0, base + 24);
        float ig = 1.f / (1.f + __expf(-gi));
        float fg = 1.f / (1.f + __expf(-gf));
        float g  = 1.f - 2.f / (__expf(2.f * gg) + 1.f);
        float og = 1.f / (1.f + __expf(-go));
        float c  = fg * c_st + ig * g;
        c_st = c;
        float h = og * (1.f - 2.f / (__expf(2.f * c) + 1.f));

        if (t == T_STEPS - 1) {
            if ((lane & 31) == 0) out[w * 8 + 2 * wv + (lane >> 5)] = h;
        } else {
            float hh = __shfl(h, 32);      // odd-m h
            if (lane == 0) {
                f16x2 hp; hp[0] = (f16)h; hp[1] = (f16)hh;
                unsigned long long val =
                    ((unsigned long long)(unsigned)(t + 2) << 32) |
                    (unsigned long long)__builtin_bit_cast(unsigned, hp);
                unsigned long long* nxt = (t & 1) ? bb0 : bb1;
                __hip_atomic_store(nxt + (w * 4 + wv), val,
                                   __ATOMIC_RELAXED, __HIP_MEMORY_SCOPE_AGENT);
            }
        }
    }
}

// ---------------------------------------------------------------------------
extern "C" void kernel_launch(void* const* d_in, const int* in_sizes, int n_in,
                              void* d_out, int out_size, void* d_ws, size_t ws_size,
                              hipStream_t stream) {
    const float* src = (const float*)d_in[0];
    const float* dst = (const float*)d_in[1];
    const float* Wih = (const float*)d_in[2];
    const float* Whh = (const float*)d_in[3];
    const float* bi  = (const float*)d_in[4];
    const float* bh  = (const float*)d_in[5];
    float* out = (float*)d_out;

    f16* xg = (f16*)d_ws;
    unsigned long long* hbuf =
        (unsigned long long*)((char*)d_ws + ((size_t)64 << 20));

    hipLaunchKernelGGL(init_tags, dim3(8), dim3(256), 0, stream, hbuf);
    hipLaunchKernelGGL(xg_gemm, dim3((4096 / GBM) * (FOURH / GBN)), dim3(256), 0, stream,
                       src, dst, Wih, bi, bh, xg);
    hipLaunchKernelGGL(lstm_scan, dim3(256), dim3(256), 0, stream, Whh, xg, hbuf, out);
}